// Round 13
// baseline (21.548 us; speedup 1.0000x reference)
//
#include <hip/hip_runtime.h>
#include <limits.h>

// BKT: B=4096 students, T=512 timesteps, K=2048 skills.
// R13 = R12 probe rerun, transcription bug fixed. R12's REAL rescan loop
// dropped the (node>>11)==s_ skill filter (needed with hashed buckets:
// skills s and s+1024 share a chain) -> alien responses replayed, absmax
// 0.877. Filter restored in both walk loops (rank walk + rescan), probe
// unchanged: duplicate walk+replay, asm-opaque head, result kept live.
// Read: dur ~26-30us => walk+replay dominates; ~16-18us => prologue does.

#define BKT_B 4096
#define BKT_T 512
#define BKT_K 2048
#define BLK   256
#define TPT   (BKT_T / BLK)   // 2 timesteps per thread
#define HASH  1024
#define PTR_END 0x3FF

__device__ __forceinline__ float bkt_update(float p, int rbit, float ss,
                                            float gg, float tt) {
  float num, den;
  if (rbit) {                // correct response
    num = p * (1.0f - ss);
    den = num + (1.0f - p) * gg;
  } else {                   // incorrect response
    num = p * ss;
    den = num + (1.0f - p) * (1.0f - gg);
  }
  const float q = num / den; // Bayesian posterior
  return q + (1.0f - q) * tt;// learning transition
}

__global__ __launch_bounds__(BLK) void bkt_kernel(
    const int* __restrict__ skills,
    const float* __restrict__ resp,
    const float* __restrict__ k0,
    const float* __restrict__ tp,
    const float* __restrict__ gp,
    const float* __restrict__ sp,
    float* __restrict__ out) {
  __shared__ int head_s[HASH];   // 4KB: last-arrival t per hash bucket, -1 empty
  __shared__ int node_s[BKT_T];  // 2KB: packed {sk, resp, prev}

  const int b = blockIdx.x;
  const int base = b * BKT_T;
  const int tid = threadIdx.x;

  int   sk[TPT];
  float rr[TPT];
  float k0v[TPT];
#pragma unroll
  for (int u = 0; u < TPT; ++u) {
    const int t = tid + u * BLK;
    sk[u] = skills[base + t];
    rr[u] = resp[base + t];
  }
#pragma unroll
  for (int u = 0; u < TPT; ++u)
    k0v[u] = k0[sk[u]];

  ((int4*)head_s)[tid] = make_int4(-1, -1, -1, -1);
  __syncthreads();

#pragma unroll
  for (int u = 0; u < TPT; ++u) {
    const int t = tid + u * BLK;
    const int s_ = sk[u];
    const int old = atomicExch(&head_s[s_ & (HASH - 1)], t);
    const int ptr = (old < 0) ? PTR_END : old;
    const int rbit = rr[u] > 0.5f ? 1 : 0;
    node_s[t] = ptr | (rbit << 10) | (s_ << 11);
  }
  __syncthreads();

#pragma unroll
  for (int u = 0; u < TPT; ++u) {
    const int t = tid + u * BLK;
    const int s_ = sk[u];
    const int head = head_s[s_ & (HASH - 1)];

    // ---- real walk + replay (identical to R10, filter in BOTH loops) ----
    int rank = 0, minj = INT_MAX, minnode = 0;
    for (int j = head; j >= 0; ) {
      const int node = node_s[j];
      if (j < t && (node >> 11) == s_) {
        ++rank;
        if (j < minj) { minj = j; minnode = node; }
      }
      const int nx = node & PTR_END;
      j = (nx == PTR_END) ? -1 : nx;
    }

    float p = k0v[u];

    if (rank > 0) {
      const float ss = sp[s_];
      const float gg = gp[s_];
      const float tt = tp[s_];
      p = bkt_update(p, (minnode >> 10) & 1, ss, gg, tt);
      int cur = minj;
      for (int rd = 1; rd < rank; ++rd) {
        int best = INT_MAX, bestnode = 0;
        for (int j = head; j >= 0; ) {
          const int node = node_s[j];
          if (j < t && j > cur && (node >> 11) == s_ && j < best) {
            best = j; bestnode = node;
          }
          const int nx = node & PTR_END;
          j = (nx == PTR_END) ? -1 : nx;
        }
        p = bkt_update(p, (bestnode >> 10) & 1, ss, gg, tt);
        cur = best;
      }
    }

    out[base + t] = p;                 // emit pre-update mastery (unchanged)

    // ---- PROBE: duplicate walk + replay, compiler-opaque, result sunk ----
    {
      int head2;
      asm volatile("v_mov_b32 %0, %1" : "=v"(head2) : "v"(head));
      int rank2 = 0, minj2 = INT_MAX, minnode2 = 0;
      for (int j = head2; j >= 0; ) {
        const int node = node_s[j];
        if (j < t && (node >> 11) == s_) {
          ++rank2;
          if (j < minj2) { minj2 = j; minnode2 = node; }
        }
        const int nx = node & PTR_END;
        j = (nx == PTR_END) ? -1 : nx;
      }

      float p2 = k0v[u];
      if (rank2 > 0) {
        const float ss = sp[s_];
        const float gg = gp[s_];
        const float tt = tp[s_];
        p2 = bkt_update(p2, (minnode2 >> 10) & 1, ss, gg, tt);
        int cur = minj2;
        for (int rd = 1; rd < rank2; ++rd) {
          int best = INT_MAX, bestnode = 0;
          for (int j = head2; j >= 0; ) {
            const int node = node_s[j];
            if (j < t && j > cur && (node >> 11) == s_ && j < best) {
              best = j; bestnode = node;
            }
            const int nx = node & PTR_END;
            j = (nx == PTR_END) ? -1 : nx;
          }
          p2 = bkt_update(p2, (bestnode >> 10) & 1, ss, gg, tt);
          cur = best;
        }
      }
      asm volatile("" :: "v"(p2));     // keep probe result live (no DCE)
    }
  }
}

extern "C" void kernel_launch(void* const* d_in, const int* in_sizes, int n_in,
                              void* d_out, int out_size, void* d_ws, size_t ws_size,
                              hipStream_t stream) {
  const int*   skills = (const int*)d_in[0];
  const float* resp   = (const float*)d_in[1];
  const float* k0     = (const float*)d_in[2];
  const float* tp     = (const float*)d_in[3];
  const float* gp     = (const float*)d_in[4];
  const float* sp     = (const float*)d_in[5];
  float* out = (float*)d_out;

  bkt_kernel<<<BKT_B, BLK, 0, stream>>>(skills, resp, k0, tp, gp, sp, out);
}